// Round 1
// baseline (578.018 us; speedup 1.0000x reference)
//
#include <hip/hip_runtime.h>
#include <hip/hip_bf16.h>

#define D 128
#define NEG_SLOPE 0.2f

// ---------------- CSR build ----------------

__global__ __launch_bounds__(256) void count_kernel(const int* __restrict__ ei,
        int* __restrict__ cnt, int e_in, int n) {
    int e = blockIdx.x * 256 + threadIdx.x;
    int tot = e_in + n;
    if (e >= tot) return;
    int d = (e < e_in) ? ei[e_in + e] : (e - e_in);
    atomicAdd(&cnt[d], 1);
}

// Single-workgroup exclusive scan over n counts -> offs[0..n] (offs[n] = total).
__global__ __launch_bounds__(1024) void scan_kernel(const int* __restrict__ cnt,
        int* __restrict__ offs, int n) {
    __shared__ int wsum[16];
    __shared__ int carry;
    if (threadIdx.x == 0) carry = 0;
    __syncthreads();
    int lane = threadIdx.x & 63;
    int wid = threadIdx.x >> 6;
    for (int base = 0; base < n; base += 1024) {
        int i = base + threadIdx.x;
        int v = (i < n) ? cnt[i] : 0;
        int x = v;
        #pragma unroll
        for (int dlt = 1; dlt < 64; dlt <<= 1) {
            int y = __shfl_up(x, dlt, 64);
            if (lane >= dlt) x += y;
        }
        if (lane == 63) wsum[wid] = x;
        __syncthreads();
        if (wid == 0) {
            int s = (lane < 16) ? wsum[lane] : 0;
            #pragma unroll
            for (int dlt = 1; dlt < 16; dlt <<= 1) {
                int y = __shfl_up(s, dlt, 64);
                if (lane >= dlt) s += y;
            }
            if (lane < 16) wsum[lane] = s;
        }
        __syncthreads();
        int bincl = x + (wid > 0 ? wsum[wid - 1] : 0);
        int excl = carry + bincl - v;
        if (i < n) offs[i] = excl;
        __syncthreads();
        if (threadIdx.x == 1023) carry += bincl;  // thread 1023's bincl = chunk total
        __syncthreads();
    }
    if (threadIdx.x == 0) offs[n] = carry;
}

__global__ __launch_bounds__(256) void scatter_kernel(const int* __restrict__ ei,
        const int* __restrict__ offs, int* __restrict__ cursor,
        int* __restrict__ csr_src, int e_in, int n) {
    int e = blockIdx.x * 256 + threadIdx.x;
    int tot = e_in + n;
    if (e >= tot) return;
    int s, d;
    if (e < e_in) { s = ei[e]; d = ei[e_in + e]; }
    else          { s = e - e_in; d = s; }
    int pos = atomicAdd(&cursor[d], 1);
    csr_src[offs[d] + pos] = s;
}

// ---------------- Per-layer kernels ----------------

// H[n x 128] = X[n x 128] @ W[128 x 128], fp32, 64-row tile, 4x8 reg blocking.
__global__ __launch_bounds__(256) void gemm_kernel(const float* __restrict__ X,
        const float* __restrict__ W, float* __restrict__ H, int n) {
    __shared__ float xs[64][36];   // stride 36: 2-way bank aliasing only (free)
    __shared__ float ws[32][128];
    int tid = threadIdx.x;
    int tx = tid & 15;   // col group: c0 = tx*8
    int ty = tid >> 4;   // row group: r0 = ty*4
    int row0 = blockIdx.x * 64;

    float acc[4][8];
    #pragma unroll
    for (int i = 0; i < 4; ++i)
        #pragma unroll
        for (int c = 0; c < 8; ++c) acc[i][c] = 0.f;

    for (int kc = 0; kc < D; kc += 32) {
        // stage X tile: 64 rows x 32 floats = 512 float4, 2 per thread
        {
            int t4 = tid;
            int r = t4 >> 3, cc = (t4 & 7) << 2;
            int grow = row0 + r;
            float4 v = make_float4(0.f, 0.f, 0.f, 0.f);
            if (grow < n) v = *(const float4*)&X[(size_t)grow * D + kc + cc];
            *(float4*)&xs[r][cc] = v;
            t4 = tid + 256;
            r = t4 >> 3; cc = (t4 & 7) << 2;
            grow = row0 + r;
            v = make_float4(0.f, 0.f, 0.f, 0.f);
            if (grow < n) v = *(const float4*)&X[(size_t)grow * D + kc + cc];
            *(float4*)&xs[r][cc] = v;
        }
        // stage W tile: 32 rows x 128 floats = 1024 float4, 4 per thread
        #pragma unroll
        for (int q = 0; q < 4; ++q) {
            int t4 = tid + q * 256;
            int r = t4 >> 5, cc = (t4 & 31) << 2;
            *(float4*)&ws[r][cc] = *(const float4*)&W[(size_t)(kc + r) * D + cc];
        }
        __syncthreads();
        #pragma unroll 8
        for (int k = 0; k < 32; ++k) {
            float xv[4];
            #pragma unroll
            for (int i = 0; i < 4; ++i) xv[i] = xs[ty * 4 + i][k];
            float4 w0 = *(float4*)&ws[k][tx * 8];
            float4 w1 = *(float4*)&ws[k][tx * 8 + 4];
            #pragma unroll
            for (int i = 0; i < 4; ++i) {
                acc[i][0] += xv[i] * w0.x;
                acc[i][1] += xv[i] * w0.y;
                acc[i][2] += xv[i] * w0.z;
                acc[i][3] += xv[i] * w0.w;
                acc[i][4] += xv[i] * w1.x;
                acc[i][5] += xv[i] * w1.y;
                acc[i][6] += xv[i] * w1.z;
                acc[i][7] += xv[i] * w1.w;
            }
        }
        __syncthreads();
    }
    #pragma unroll
    for (int i = 0; i < 4; ++i) {
        int row = row0 + ty * 4 + i;
        if (row < n) {
            *(float4*)&H[(size_t)row * D + tx * 8] =
                make_float4(acc[i][0], acc[i][1], acc[i][2], acc[i][3]);
            *(float4*)&H[(size_t)row * D + tx * 8 + 4] =
                make_float4(acc[i][4], acc[i][5], acc[i][6], acc[i][7]);
        }
    }
}

// hs[i] = h[i,:]·a_src, hd[i] = h[i,:]·a_dst. One wave per node.
__global__ __launch_bounds__(256) void hsd_kernel(const float* __restrict__ h,
        const float* __restrict__ a_src, const float* __restrict__ a_dst,
        float* __restrict__ hs, float* __restrict__ hd, int n) {
    int node = blockIdx.x * 4 + (threadIdx.x >> 6);
    if (node >= n) return;
    int lane = threadIdx.x & 63;
    float2 hv = ((const float2*)(h + (size_t)node * D))[lane];
    float2 as = ((const float2*)a_src)[lane];
    float2 ad = ((const float2*)a_dst)[lane];
    float ps = hv.x * as.x + hv.y * as.y;
    float pd = hv.x * ad.x + hv.y * ad.y;
    #pragma unroll
    for (int dlt = 32; dlt > 0; dlt >>= 1) {
        ps += __shfl_down(ps, dlt, 64);
        pd += __shfl_down(pd, dlt, 64);
    }
    if (lane == 0) { hs[node] = ps; hd[node] = pd; }
}

// One wave per destination node: fused softmax (max-free) + weighted aggregate.
__global__ __launch_bounds__(256) void aggregate_kernel(const float* __restrict__ h,
        const float* __restrict__ hs, const float* __restrict__ hd,
        const int* __restrict__ offs, const int* __restrict__ csr_src,
        const float* __restrict__ bias, float* __restrict__ out, int n) {
    int node = blockIdx.x * 4 + (threadIdx.x >> 6);
    if (node >= n) return;
    int lane = threadIdx.x & 63;
    int beg = offs[node], end = offs[node + 1];
    float hdn = hd[node];
    float accx = 0.f, accy = 0.f, z = 0.f;
    for (int j = beg; j < end; ++j) {
        int s = csr_src[j];
        float e = hs[s] + hdn;
        e = e > 0.f ? e : NEG_SLOPE * e;
        float wv = __expf(e);
        float2 hv = ((const float2*)(h + (size_t)s * D))[lane];
        accx = fmaf(wv, hv.x, accx);
        accy = fmaf(wv, hv.y, accy);
        z += wv;
    }
    float inv = 1.0f / z;   // every node has a self-loop -> z > 0
    float2 bv = ((const float2*)bias)[lane];
    float ox = accx * inv + bv.x;
    float oy = accy * inv + bv.y;
    ox = ox > 0.f ? ox : 0.f;
    oy = oy > 0.f ? oy : 0.f;
    float2 o; o.x = ox; o.y = oy;
    ((float2*)(out + (size_t)node * D))[lane] = o;
}

// ---------------- Orchestration ----------------

extern "C" void kernel_launch(void* const* d_in, const int* in_sizes, int n_in,
                              void* d_out, int out_size, void* d_ws, size_t ws_size,
                              hipStream_t stream) {
    const float* x      = (const float*)d_in[0];
    const int*   ei     = (const int*)d_in[1];
    const float* W1     = (const float*)d_in[2];
    const float* a_src1 = (const float*)d_in[3];
    const float* a_dst1 = (const float*)d_in[4];
    const float* b1     = (const float*)d_in[5];
    const float* W2     = (const float*)d_in[6];
    const float* a_src2 = (const float*)d_in[7];
    const float* a_dst2 = (const float*)d_in[8];
    const float* b2     = (const float*)d_in[9];

    int n    = in_sizes[0] / D;       // 100000
    int e_in = in_sizes[1] / 2;       // 625000
    int e_tot = e_in + n;             // 725000

    // ws layout (all fp32/int32): h | hs | hd | cnt | offs(n+1) | cursor | csr
    float* h      = (float*)d_ws;
    float* hs     = h + (size_t)n * D;
    float* hd     = hs + n;
    int*   cnt    = (int*)(hd + n);
    int*   offs   = cnt + n;
    int*   cursor = offs + n + 1;
    int*   csr    = cursor + n;
    float* t      = (float*)d_out;    // layer-1 output aliases d_out (safe: layer-2
                                      // aggregate reads only h/hs/hd, writes d_out)

    int eb = (e_tot + 255) / 256;
    int nb4 = (n + 3) / 4;
    int gb = (n + 63) / 64;

    hipMemsetAsync(cnt, 0, (size_t)n * sizeof(int), stream);
    hipMemsetAsync(cursor, 0, (size_t)n * sizeof(int), stream);
    count_kernel<<<eb, 256, 0, stream>>>(ei, cnt, e_in, n);
    scan_kernel<<<1, 1024, 0, stream>>>(cnt, offs, n);
    scatter_kernel<<<eb, 256, 0, stream>>>(ei, offs, cursor, csr, e_in, n);

    // Layer 1
    gemm_kernel<<<gb, 256, 0, stream>>>(x, W1, h, n);
    hsd_kernel<<<nb4, 256, 0, stream>>>(h, a_src1, a_dst1, hs, hd, n);
    aggregate_kernel<<<nb4, 256, 0, stream>>>(h, hs, hd, offs, csr, b1, t, n);

    // Layer 2
    gemm_kernel<<<gb, 256, 0, stream>>>(t, W2, h, n);
    hsd_kernel<<<nb4, 256, 0, stream>>>(h, a_src2, a_dst2, hs, hd, n);
    aggregate_kernel<<<nb4, 256, 0, stream>>>(h, hs, hd, offs, csr, b2, (float*)d_out, n);
}

// Round 2
// 457.088 us; speedup vs baseline: 1.2646x; 1.2646x over previous
//
#include <hip/hip_runtime.h>
#include <hip/hip_bf16.h>

#define D 128
#define NEG_SLOPE 0.2f
#define SCAN_CHUNK 4096   // elements per block in hierarchical scan

// ---------------- CSR build ----------------

__global__ __launch_bounds__(256) void count_kernel(const int* __restrict__ ei,
        int* __restrict__ cnt, int e_in, int n) {
    int e = blockIdx.x * 256 + threadIdx.x;
    int tot = e_in + n;
    if (e >= tot) return;
    int d = (e < e_in) ? ei[e_in + e] : (e - e_in);
    atomicAdd(&cnt[d], 1);
}

// Pass 1: per-block reduce of SCAN_CHUNK counts -> blocksum[b]
__global__ __launch_bounds__(1024) void scan_reduce_kernel(const int* __restrict__ cnt,
        int* __restrict__ blocksum, int n) {
    __shared__ int wsum[16];
    int b = blockIdx.x;
    int base = b * SCAN_CHUNK;
    int t = threadIdx.x;
    int s = 0;
    #pragma unroll
    for (int j = 0; j < 4; ++j) {
        int i = base + t * 4 + j;
        if (i < n) s += cnt[i];
    }
    int lane = t & 63, wid = t >> 6;
    #pragma unroll
    for (int dlt = 32; dlt > 0; dlt >>= 1) s += __shfl_down(s, dlt, 64);
    if (lane == 0) wsum[wid] = s;
    __syncthreads();
    if (t == 0) {
        int tot = 0;
        #pragma unroll
        for (int w = 0; w < 16; ++w) tot += wsum[w];
        blocksum[b] = tot;
    }
}

// Pass 2: single-block exclusive scan over nb blocksums -> blockoffs[0..nb],
// also writes offs[n] = grand total.
__global__ __launch_bounds__(1024) void scan_blocksums_kernel(const int* __restrict__ blocksum,
        int* __restrict__ blockoffs, int* __restrict__ offs, int nb, int n) {
    __shared__ int wsum[16];
    __shared__ int carry;
    if (threadIdx.x == 0) carry = 0;
    __syncthreads();
    int lane = threadIdx.x & 63;
    int wid = threadIdx.x >> 6;
    for (int base = 0; base < nb; base += 1024) {
        int i = base + threadIdx.x;
        int v = (i < nb) ? blocksum[i] : 0;
        int x = v;
        #pragma unroll
        for (int dlt = 1; dlt < 64; dlt <<= 1) {
            int y = __shfl_up(x, dlt, 64);
            if (lane >= dlt) x += y;
        }
        if (lane == 63) wsum[wid] = x;
        __syncthreads();
        if (wid == 0) {
            int s = (lane < 16) ? wsum[lane] : 0;
            #pragma unroll
            for (int dlt = 1; dlt < 16; dlt <<= 1) {
                int y = __shfl_up(s, dlt, 64);
                if (lane >= dlt) s += y;
            }
            if (lane < 16) wsum[lane] = s;
        }
        __syncthreads();
        int bincl = x + (wid > 0 ? wsum[wid - 1] : 0);
        int excl = carry + bincl - v;
        if (i < nb) blockoffs[i] = excl;
        __syncthreads();
        if (threadIdx.x == 1023) carry += bincl;
        __syncthreads();
    }
    if (threadIdx.x == 0) { blockoffs[nb] = carry; offs[n] = carry; }
}

// Pass 3: per-block exclusive scan of its chunk + blockoffs[b] -> offs
__global__ __launch_bounds__(1024) void scan_final_kernel(const int* __restrict__ cnt,
        const int* __restrict__ blockoffs, int* __restrict__ offs, int n) {
    __shared__ int wsum[16];
    int b = blockIdx.x;
    int base = b * SCAN_CHUNK;
    int t = threadIdx.x;
    int i0 = base + t * 4;
    int v[4];
    #pragma unroll
    for (int j = 0; j < 4; ++j) v[j] = (i0 + j < n) ? cnt[i0 + j] : 0;
    int tsum = v[0] + v[1] + v[2] + v[3];
    int lane = t & 63, wid = t >> 6;
    int x = tsum;
    #pragma unroll
    for (int dlt = 1; dlt < 64; dlt <<= 1) {
        int y = __shfl_up(x, dlt, 64);
        if (lane >= dlt) x += y;
    }
    if (lane == 63) wsum[wid] = x;
    __syncthreads();
    if (wid == 0) {
        int s = (lane < 16) ? wsum[lane] : 0;
        #pragma unroll
        for (int dlt = 1; dlt < 16; dlt <<= 1) {
            int y = __shfl_up(s, dlt, 64);
            if (lane >= dlt) s += y;
        }
        if (lane < 16) wsum[lane] = s;
    }
    __syncthreads();
    int incl = x + (wid > 0 ? wsum[wid - 1] : 0);
    int excl = blockoffs[b] + incl - tsum;
    #pragma unroll
    for (int j = 0; j < 4; ++j) {
        if (i0 + j < n) offs[i0 + j] = excl;
        excl += v[j];
    }
}

__global__ __launch_bounds__(256) void scatter_kernel(const int* __restrict__ ei,
        const int* __restrict__ offs, int* __restrict__ cursor,
        int* __restrict__ csr_src, int e_in, int n) {
    int e = blockIdx.x * 256 + threadIdx.x;
    int tot = e_in + n;
    if (e >= tot) return;
    int s, d;
    if (e < e_in) { s = ei[e]; d = ei[e_in + e]; }
    else          { s = e - e_in; d = s; }
    int pos = atomicAdd(&cursor[d], 1);
    csr_src[offs[d] + pos] = s;
}

// ---------------- Per-layer kernels ----------------

// H[n x 128] = X[n x 128] @ W[128 x 128] fp32, 64-row tile, 4x8 reg blocking.
// Fused epilogue: hs[row] = H[row,:]·a_src, hd[row] = H[row,:]·a_dst.
__global__ __launch_bounds__(256) void gemm_kernel(const float* __restrict__ X,
        const float* __restrict__ W, const float* __restrict__ a_src,
        const float* __restrict__ a_dst, float* __restrict__ H,
        float* __restrict__ hs, float* __restrict__ hd, int n) {
    __shared__ float xs[64][36];   // stride 36: 2-way bank aliasing only (free)
    __shared__ float ws[32][128];
    int tid = threadIdx.x;
    int tx = tid & 15;   // col group: c0 = tx*8
    int ty = tid >> 4;   // row group: r0 = ty*4
    int row0 = blockIdx.x * 64;

    float acc[4][8];
    #pragma unroll
    for (int i = 0; i < 4; ++i)
        #pragma unroll
        for (int c = 0; c < 8; ++c) acc[i][c] = 0.f;

    for (int kc = 0; kc < D; kc += 32) {
        {
            int t4 = tid;
            int r = t4 >> 3, cc = (t4 & 7) << 2;
            int grow = row0 + r;
            float4 v = make_float4(0.f, 0.f, 0.f, 0.f);
            if (grow < n) v = *(const float4*)&X[(size_t)grow * D + kc + cc];
            *(float4*)&xs[r][cc] = v;
            t4 = tid + 256;
            r = t4 >> 3; cc = (t4 & 7) << 2;
            grow = row0 + r;
            v = make_float4(0.f, 0.f, 0.f, 0.f);
            if (grow < n) v = *(const float4*)&X[(size_t)grow * D + kc + cc];
            *(float4*)&xs[r][cc] = v;
        }
        #pragma unroll
        for (int q = 0; q < 4; ++q) {
            int t4 = tid + q * 256;
            int r = t4 >> 5, cc = (t4 & 31) << 2;
            *(float4*)&ws[r][cc] = *(const float4*)&W[(size_t)(kc + r) * D + cc];
        }
        __syncthreads();
        #pragma unroll 8
        for (int k = 0; k < 32; ++k) {
            float xv[4];
            #pragma unroll
            for (int i = 0; i < 4; ++i) xv[i] = xs[ty * 4 + i][k];
            float4 w0 = *(float4*)&ws[k][tx * 8];
            float4 w1 = *(float4*)&ws[k][tx * 8 + 4];
            #pragma unroll
            for (int i = 0; i < 4; ++i) {
                acc[i][0] += xv[i] * w0.x;
                acc[i][1] += xv[i] * w0.y;
                acc[i][2] += xv[i] * w0.z;
                acc[i][3] += xv[i] * w0.w;
                acc[i][4] += xv[i] * w1.x;
                acc[i][5] += xv[i] * w1.y;
                acc[i][6] += xv[i] * w1.z;
                acc[i][7] += xv[i] * w1.w;
            }
        }
        __syncthreads();
    }

    // epilogue: store H + fused attention dots
    float4 as0 = *(const float4*)&a_src[tx * 8];
    float4 as1 = *(const float4*)&a_src[tx * 8 + 4];
    float4 ad0 = *(const float4*)&a_dst[tx * 8];
    float4 ad1 = *(const float4*)&a_dst[tx * 8 + 4];
    #pragma unroll
    for (int i = 0; i < 4; ++i) {
        int row = row0 + ty * 4 + i;
        if (row < n) {
            *(float4*)&H[(size_t)row * D + tx * 8] =
                make_float4(acc[i][0], acc[i][1], acc[i][2], acc[i][3]);
            *(float4*)&H[(size_t)row * D + tx * 8 + 4] =
                make_float4(acc[i][4], acc[i][5], acc[i][6], acc[i][7]);
        }
        float ps = acc[i][0] * as0.x + acc[i][1] * as0.y + acc[i][2] * as0.z +
                   acc[i][3] * as0.w + acc[i][4] * as1.x + acc[i][5] * as1.y +
                   acc[i][6] * as1.z + acc[i][7] * as1.w;
        float pd = acc[i][0] * ad0.x + acc[i][1] * ad0.y + acc[i][2] * ad0.z +
                   acc[i][3] * ad0.w + acc[i][4] * ad1.x + acc[i][5] * ad1.y +
                   acc[i][6] * ad1.z + acc[i][7] * ad1.w;
        // reduce across tx (16 consecutive lanes share the same ty)
        #pragma unroll
        for (int dlt = 8; dlt > 0; dlt >>= 1) {
            ps += __shfl_down(ps, dlt, 16);
            pd += __shfl_down(pd, dlt, 16);
        }
        if (tx == 0 && row < n) { hs[row] = ps; hd[row] = pd; }
    }
}

// One wave per destination node: fused softmax (max-free) + weighted aggregate.
__global__ __launch_bounds__(256) void aggregate_kernel(const float* __restrict__ h,
        const float* __restrict__ hs, const float* __restrict__ hd,
        const int* __restrict__ offs, const int* __restrict__ csr_src,
        const float* __restrict__ bias, float* __restrict__ out, int n) {
    int node = blockIdx.x * 4 + (threadIdx.x >> 6);
    if (node >= n) return;
    int lane = threadIdx.x & 63;
    int beg = offs[node], end = offs[node + 1];
    float hdn = hd[node];
    float accx = 0.f, accy = 0.f, z = 0.f;
    for (int j = beg; j < end; ++j) {
        int s = csr_src[j];
        float e = hs[s] + hdn;
        e = e > 0.f ? e : NEG_SLOPE * e;
        float wv = __expf(e);
        float2 hv = ((const float2*)(h + (size_t)s * D))[lane];
        accx = fmaf(wv, hv.x, accx);
        accy = fmaf(wv, hv.y, accy);
        z += wv;
    }
    float inv = 1.0f / z;   // every node has a self-loop -> z > 0
    float2 bv = ((const float2*)bias)[lane];
    float ox = accx * inv + bv.x;
    float oy = accy * inv + bv.y;
    ox = ox > 0.f ? ox : 0.f;
    oy = oy > 0.f ? oy : 0.f;
    float2 o; o.x = ox; o.y = oy;
    ((float2*)(out + (size_t)node * D))[lane] = o;
}

// ---------------- Orchestration ----------------

extern "C" void kernel_launch(void* const* d_in, const int* in_sizes, int n_in,
                              void* d_out, int out_size, void* d_ws, size_t ws_size,
                              hipStream_t stream) {
    const float* x      = (const float*)d_in[0];
    const int*   ei     = (const int*)d_in[1];
    const float* W1     = (const float*)d_in[2];
    const float* a_src1 = (const float*)d_in[3];
    const float* a_dst1 = (const float*)d_in[4];
    const float* b1     = (const float*)d_in[5];
    const float* W2     = (const float*)d_in[6];
    const float* a_src2 = (const float*)d_in[7];
    const float* a_dst2 = (const float*)d_in[8];
    const float* b2     = (const float*)d_in[9];

    int n    = in_sizes[0] / D;       // 100000
    int e_in = in_sizes[1] / 2;       // 625000
    int e_tot = e_in + n;             // 725000
    int nsb = (n + SCAN_CHUNK - 1) / SCAN_CHUNK;   // scan blocks (25)

    // ws layout: h | hs | hd | cnt | offs(n+1) | cursor | blocksum(nsb) | blockoffs(nsb+1) | csr
    float* h        = (float*)d_ws;
    float* hs       = h + (size_t)n * D;
    float* hd       = hs + n;
    int*   cnt      = (int*)(hd + n);
    int*   offs     = cnt + n;
    int*   cursor   = offs + n + 1;
    int*   blocksum = cursor + n;
    int*   blockoffs= blocksum + nsb;
    int*   csr      = blockoffs + nsb + 1;
    float* t        = (float*)d_out;  // layer-1 output aliases d_out

    int eb = (e_tot + 255) / 256;
    int nb4 = (n + 3) / 4;
    int gb = (n + 63) / 64;

    hipMemsetAsync(cnt, 0, (size_t)n * sizeof(int), stream);
    hipMemsetAsync(cursor, 0, (size_t)n * sizeof(int), stream);
    count_kernel<<<eb, 256, 0, stream>>>(ei, cnt, e_in, n);
    scan_reduce_kernel<<<nsb, 1024, 0, stream>>>(cnt, blocksum, n);
    scan_blocksums_kernel<<<1, 1024, 0, stream>>>(blocksum, blockoffs, offs, nsb, n);
    scan_final_kernel<<<nsb, 1024, 0, stream>>>(cnt, blockoffs, offs, n);
    scatter_kernel<<<eb, 256, 0, stream>>>(ei, offs, cursor, csr, e_in, n);

    // Layer 1
    gemm_kernel<<<gb, 256, 0, stream>>>(x, W1, a_src1, a_dst1, h, hs, hd, n);
    aggregate_kernel<<<nb4, 256, 0, stream>>>(h, hs, hd, offs, csr, b1, t, n);

    // Layer 2
    gemm_kernel<<<gb, 256, 0, stream>>>(t, W2, a_src2, a_dst2, h, hs, hd, n);
    aggregate_kernel<<<nb4, 256, 0, stream>>>(h, hs, hd, offs, csr, b2, (float*)d_out, n);
}

// Round 3
// 386.389 us; speedup vs baseline: 1.4959x; 1.1830x over previous
//
#include <hip/hip_runtime.h>
#include <hip/hip_bf16.h>

#define D 128
#define NEG_SLOPE 0.2f
#define SCAN_CHUNK 4096   // elements per block in hierarchical scan

// ---------------- CSR build ----------------

__global__ __launch_bounds__(256) void count_kernel(const int* __restrict__ ei,
        int* __restrict__ cnt, int e_in, int n) {
    int e = blockIdx.x * 256 + threadIdx.x;
    int tot = e_in + n;
    if (e >= tot) return;
    int d = (e < e_in) ? ei[e_in + e] : (e - e_in);
    atomicAdd(&cnt[d], 1);
}

// Pass 1: per-block reduce of SCAN_CHUNK counts -> blocksum[b]
__global__ __launch_bounds__(1024) void scan_reduce_kernel(const int* __restrict__ cnt,
        int* __restrict__ blocksum, int n) {
    __shared__ int wsum[16];
    int b = blockIdx.x;
    int base = b * SCAN_CHUNK;
    int t = threadIdx.x;
    int s = 0;
    #pragma unroll
    for (int j = 0; j < 4; ++j) {
        int i = base + t * 4 + j;
        if (i < n) s += cnt[i];
    }
    int lane = t & 63, wid = t >> 6;
    #pragma unroll
    for (int dlt = 32; dlt > 0; dlt >>= 1) s += __shfl_down(s, dlt, 64);
    if (lane == 0) wsum[wid] = s;
    __syncthreads();
    if (t == 0) {
        int tot = 0;
        #pragma unroll
        for (int w = 0; w < 16; ++w) tot += wsum[w];
        blocksum[b] = tot;
    }
}

// Pass 2: single-block exclusive scan over nb blocksums -> blockoffs[0..nb],
// also writes offs[n] = grand total.
__global__ __launch_bounds__(1024) void scan_blocksums_kernel(const int* __restrict__ blocksum,
        int* __restrict__ blockoffs, int* __restrict__ offs, int nb, int n) {
    __shared__ int wsum[16];
    __shared__ int carry;
    if (threadIdx.x == 0) carry = 0;
    __syncthreads();
    int lane = threadIdx.x & 63;
    int wid = threadIdx.x >> 6;
    for (int base = 0; base < nb; base += 1024) {
        int i = base + threadIdx.x;
        int v = (i < nb) ? blocksum[i] : 0;
        int x = v;
        #pragma unroll
        for (int dlt = 1; dlt < 64; dlt <<= 1) {
            int y = __shfl_up(x, dlt, 64);
            if (lane >= dlt) x += y;
        }
        if (lane == 63) wsum[wid] = x;
        __syncthreads();
        if (wid == 0) {
            int s = (lane < 16) ? wsum[lane] : 0;
            #pragma unroll
            for (int dlt = 1; dlt < 16; dlt <<= 1) {
                int y = __shfl_up(s, dlt, 64);
                if (lane >= dlt) s += y;
            }
            if (lane < 16) wsum[lane] = s;
        }
        __syncthreads();
        int bincl = x + (wid > 0 ? wsum[wid - 1] : 0);
        int excl = carry + bincl - v;
        if (i < nb) blockoffs[i] = excl;
        __syncthreads();
        if (threadIdx.x == 1023) carry += bincl;
        __syncthreads();
    }
    if (threadIdx.x == 0) { blockoffs[nb] = carry; offs[n] = carry; }
}

// Pass 3: per-block exclusive scan of its chunk + blockoffs[b] -> offs
__global__ __launch_bounds__(1024) void scan_final_kernel(const int* __restrict__ cnt,
        const int* __restrict__ blockoffs, int* __restrict__ offs, int n) {
    __shared__ int wsum[16];
    int b = blockIdx.x;
    int base = b * SCAN_CHUNK;
    int t = threadIdx.x;
    int i0 = base + t * 4;
    int v[4];
    #pragma unroll
    for (int j = 0; j < 4; ++j) v[j] = (i0 + j < n) ? cnt[i0 + j] : 0;
    int tsum = v[0] + v[1] + v[2] + v[3];
    int lane = t & 63, wid = t >> 6;
    int x = tsum;
    #pragma unroll
    for (int dlt = 1; dlt < 64; dlt <<= 1) {
        int y = __shfl_up(x, dlt, 64);
        if (lane >= dlt) x += y;
    }
    if (lane == 63) wsum[wid] = x;
    __syncthreads();
    if (wid == 0) {
        int s = (lane < 16) ? wsum[lane] : 0;
        #pragma unroll
        for (int dlt = 1; dlt < 16; dlt <<= 1) {
            int y = __shfl_up(s, dlt, 64);
            if (lane >= dlt) s += y;
        }
        if (lane < 16) wsum[lane] = s;
    }
    __syncthreads();
    int incl = x + (wid > 0 ? wsum[wid - 1] : 0);
    int excl = blockoffs[b] + incl - tsum;
    #pragma unroll
    for (int j = 0; j < 4; ++j) {
        if (i0 + j < n) offs[i0 + j] = excl;
        excl += v[j];
    }
}

__global__ __launch_bounds__(256) void scatter_kernel(const int* __restrict__ ei,
        const int* __restrict__ offs, int* __restrict__ cursor,
        int* __restrict__ csr_src, int e_in, int n) {
    int e = blockIdx.x * 256 + threadIdx.x;
    int tot = e_in + n;
    if (e >= tot) return;
    int s, d;
    if (e < e_in) { s = ei[e]; d = ei[e_in + e]; }
    else          { s = e - e_in; d = s; }
    int pos = atomicAdd(&cursor[d], 1);
    csr_src[offs[d] + pos] = s;
}

// ---------------- Per-layer kernels ----------------

// H[n x 128](bf16) = X[n x 128](fp32) @ W[128 x 128](fp32).
// Fused epilogue: hs[row] = H_f32[row,:]·a_src, hd[row] = H_f32[row,:]·a_dst
// (computed from fp32 accumulators — attention logits stay full precision).
__global__ __launch_bounds__(256) void gemm_kernel(const float* __restrict__ X,
        const float* __restrict__ W, const float* __restrict__ a_src,
        const float* __restrict__ a_dst, __hip_bfloat16* __restrict__ H,
        float* __restrict__ hs, float* __restrict__ hd, int n) {
    __shared__ float xs[64][36];   // stride 36: 2-way bank aliasing only (free)
    __shared__ float ws[32][128];
    int tid = threadIdx.x;
    int tx = tid & 15;   // col group: c0 = tx*8
    int ty = tid >> 4;   // row group: r0 = ty*4
    int row0 = blockIdx.x * 64;

    float acc[4][8];
    #pragma unroll
    for (int i = 0; i < 4; ++i)
        #pragma unroll
        for (int c = 0; c < 8; ++c) acc[i][c] = 0.f;

    for (int kc = 0; kc < D; kc += 32) {
        {
            int t4 = tid;
            int r = t4 >> 3, cc = (t4 & 7) << 2;
            int grow = row0 + r;
            float4 v = make_float4(0.f, 0.f, 0.f, 0.f);
            if (grow < n) v = *(const float4*)&X[(size_t)grow * D + kc + cc];
            *(float4*)&xs[r][cc] = v;
            t4 = tid + 256;
            r = t4 >> 3; cc = (t4 & 7) << 2;
            grow = row0 + r;
            v = make_float4(0.f, 0.f, 0.f, 0.f);
            if (grow < n) v = *(const float4*)&X[(size_t)grow * D + kc + cc];
            *(float4*)&xs[r][cc] = v;
        }
        #pragma unroll
        for (int q = 0; q < 4; ++q) {
            int t4 = tid + q * 256;
            int r = t4 >> 5, cc = (t4 & 31) << 2;
            *(float4*)&ws[r][cc] = *(const float4*)&W[(size_t)(kc + r) * D + cc];
        }
        __syncthreads();
        #pragma unroll 8
        for (int k = 0; k < 32; ++k) {
            float xv[4];
            #pragma unroll
            for (int i = 0; i < 4; ++i) xv[i] = xs[ty * 4 + i][k];
            float4 w0 = *(float4*)&ws[k][tx * 8];
            float4 w1 = *(float4*)&ws[k][tx * 8 + 4];
            #pragma unroll
            for (int i = 0; i < 4; ++i) {
                acc[i][0] += xv[i] * w0.x;
                acc[i][1] += xv[i] * w0.y;
                acc[i][2] += xv[i] * w0.z;
                acc[i][3] += xv[i] * w0.w;
                acc[i][4] += xv[i] * w1.x;
                acc[i][5] += xv[i] * w1.y;
                acc[i][6] += xv[i] * w1.z;
                acc[i][7] += xv[i] * w1.w;
            }
        }
        __syncthreads();
    }

    // epilogue: store H (bf16) + fused attention dots (fp32)
    float4 as0 = *(const float4*)&a_src[tx * 8];
    float4 as1 = *(const float4*)&a_src[tx * 8 + 4];
    float4 ad0 = *(const float4*)&a_dst[tx * 8];
    float4 ad1 = *(const float4*)&a_dst[tx * 8 + 4];
    #pragma unroll
    for (int i = 0; i < 4; ++i) {
        int row = row0 + ty * 4 + i;
        if (row < n) {
            __hip_bfloat16 hb[8];
            #pragma unroll
            for (int c = 0; c < 8; ++c) hb[c] = __float2bfloat16(acc[i][c]);
            *(uint4*)&H[(size_t)row * D + tx * 8] = *(const uint4*)hb;
        }
        float ps = acc[i][0] * as0.x + acc[i][1] * as0.y + acc[i][2] * as0.z +
                   acc[i][3] * as0.w + acc[i][4] * as1.x + acc[i][5] * as1.y +
                   acc[i][6] * as1.z + acc[i][7] * as1.w;
        float pd = acc[i][0] * ad0.x + acc[i][1] * ad0.y + acc[i][2] * ad0.z +
                   acc[i][3] * ad0.w + acc[i][4] * ad1.x + acc[i][5] * ad1.y +
                   acc[i][6] * ad1.z + acc[i][7] * ad1.w;
        #pragma unroll
        for (int dlt = 8; dlt > 0; dlt >>= 1) {
            ps += __shfl_down(ps, dlt, 16);
            pd += __shfl_down(pd, dlt, 16);
        }
        if (tx == 0 && row < n) { hs[row] = ps; hd[row] = pd; }
    }
}

// One wave per destination node; 4 edges in flight per trip.
// Lane = (group g=lane>>4 : edge slot, gl=lane&15 : 8 bf16 = 16B of the row).
__global__ __launch_bounds__(256) void aggregate_kernel(
        const __hip_bfloat16* __restrict__ h, const float* __restrict__ hs,
        const float* __restrict__ hd, const int* __restrict__ offs,
        const int* __restrict__ csr_src, const float* __restrict__ bias,
        float* __restrict__ out, int n) {
    int node = blockIdx.x * 4 + (threadIdx.x >> 6);
    if (node >= n) return;
    int lane = threadIdx.x & 63;
    int grp = lane >> 4;
    int gl = lane & 15;
    int beg = offs[node], end = offs[node + 1];
    float hdn = hd[node];
    const uint* hp = (const uint*)h;   // 2 bf16 per uint, row stride 64 uints

    float acc[8] = {0.f, 0.f, 0.f, 0.f, 0.f, 0.f, 0.f, 0.f};
    float z = 0.f;
    for (int j = beg; j < end; j += 4) {
        int jj = j + grp;
        bool act = jj < end;
        int s = act ? csr_src[jj] : node;
        float e = hs[s] + hdn;
        e = e > 0.f ? e : NEG_SLOPE * e;
        float wv = act ? __expf(e) : 0.f;
        uint4 raw = *(const uint4*)(hp + ((size_t)s << 6) + (gl << 2));
        float f0 = __uint_as_float(raw.x << 16);
        float f1 = __uint_as_float(raw.x & 0xffff0000u);
        float f2 = __uint_as_float(raw.y << 16);
        float f3 = __uint_as_float(raw.y & 0xffff0000u);
        float f4 = __uint_as_float(raw.z << 16);
        float f5 = __uint_as_float(raw.z & 0xffff0000u);
        float f6 = __uint_as_float(raw.w << 16);
        float f7 = __uint_as_float(raw.w & 0xffff0000u);
        acc[0] = fmaf(wv, f0, acc[0]);
        acc[1] = fmaf(wv, f1, acc[1]);
        acc[2] = fmaf(wv, f2, acc[2]);
        acc[3] = fmaf(wv, f3, acc[3]);
        acc[4] = fmaf(wv, f4, acc[4]);
        acc[5] = fmaf(wv, f5, acc[5]);
        acc[6] = fmaf(wv, f6, acc[6]);
        acc[7] = fmaf(wv, f7, acc[7]);
        z += wv;
    }
    // combine the 4 edge groups -> lanes 0..15 hold the full row
    #pragma unroll
    for (int dlt = 32; dlt >= 16; dlt >>= 1) {
        #pragma unroll
        for (int k = 0; k < 8; ++k) acc[k] += __shfl_down(acc[k], dlt, 64);
        z += __shfl_down(z, dlt, 64);
    }
    if (lane < 16) {
        float inv = 1.0f / z;   // self-loop guarantees z > 0
        float4 b0 = *(const float4*)&bias[lane * 8];
        float4 b1 = *(const float4*)&bias[lane * 8 + 4];
        float o[8];
        o[0] = acc[0] * inv + b0.x; o[1] = acc[1] * inv + b0.y;
        o[2] = acc[2] * inv + b0.z; o[3] = acc[3] * inv + b0.w;
        o[4] = acc[4] * inv + b1.x; o[5] = acc[5] * inv + b1.y;
        o[6] = acc[6] * inv + b1.z; o[7] = acc[7] * inv + b1.w;
        #pragma unroll
        for (int k = 0; k < 8; ++k) o[k] = o[k] > 0.f ? o[k] : 0.f;
        float* op = out + (size_t)node * D + lane * 8;
        *(float4*)op = make_float4(o[0], o[1], o[2], o[3]);
        *(float4*)(op + 4) = make_float4(o[4], o[5], o[6], o[7]);
    }
}

// ---------------- Orchestration ----------------

extern "C" void kernel_launch(void* const* d_in, const int* in_sizes, int n_in,
                              void* d_out, int out_size, void* d_ws, size_t ws_size,
                              hipStream_t stream) {
    const float* x      = (const float*)d_in[0];
    const int*   ei     = (const int*)d_in[1];
    const float* W1     = (const float*)d_in[2];
    const float* a_src1 = (const float*)d_in[3];
    const float* a_dst1 = (const float*)d_in[4];
    const float* b1     = (const float*)d_in[5];
    const float* W2     = (const float*)d_in[6];
    const float* a_src2 = (const float*)d_in[7];
    const float* a_dst2 = (const float*)d_in[8];
    const float* b2     = (const float*)d_in[9];

    int n    = in_sizes[0] / D;       // 100000
    int e_in = in_sizes[1] / 2;       // 625000
    int e_tot = e_in + n;             // 725000
    int nsb = (n + SCAN_CHUNK - 1) / SCAN_CHUNK;

    // ws layout: h(bf16) | hs | hd | cnt | offs(n+1) | cursor | blocksum | blockoffs | csr
    __hip_bfloat16* h = (__hip_bfloat16*)d_ws;
    float* hs       = (float*)(h + (size_t)n * D);
    float* hd       = hs + n;
    int*   cnt      = (int*)(hd + n);
    int*   offs     = cnt + n;
    int*   cursor   = offs + n + 1;
    int*   blocksum = cursor + n;
    int*   blockoffs= blocksum + nsb;
    int*   csr      = blockoffs + nsb + 1;
    float* t        = (float*)d_out;  // layer-1 output aliases d_out

    int eb = (e_tot + 255) / 256;
    int nb4 = (n + 3) / 4;
    int gb = (n + 63) / 64;

    hipMemsetAsync(cnt, 0, (size_t)n * sizeof(int), stream);
    hipMemsetAsync(cursor, 0, (size_t)n * sizeof(int), stream);
    count_kernel<<<eb, 256, 0, stream>>>(ei, cnt, e_in, n);
    scan_reduce_kernel<<<nsb, 1024, 0, stream>>>(cnt, blocksum, n);
    scan_blocksums_kernel<<<1, 1024, 0, stream>>>(blocksum, blockoffs, offs, nsb, n);
    scan_final_kernel<<<nsb, 1024, 0, stream>>>(cnt, blockoffs, offs, n);
    scatter_kernel<<<eb, 256, 0, stream>>>(ei, offs, cursor, csr, e_in, n);

    // Layer 1
    gemm_kernel<<<gb, 256, 0, stream>>>(x, W1, a_src1, a_dst1, h, hs, hd, n);
    aggregate_kernel<<<nb4, 256, 0, stream>>>(h, hs, hd, offs, csr, b1, t, n);

    // Layer 2
    gemm_kernel<<<gb, 256, 0, stream>>>(t, W2, a_src2, a_dst2, h, hs, hd, n);
    aggregate_kernel<<<nb4, 256, 0, stream>>>(h, hs, hd, offs, csr, b2, (float*)d_out, n);
}

// Round 4
// 366.255 us; speedup vs baseline: 1.5782x; 1.0550x over previous
//
#include <hip/hip_runtime.h>
#include <hip/hip_bf16.h>

#define D 128
#define NEG_SLOPE 0.2f
#define SCAN_CHUNK 4096   // elements per block in hierarchical scan

using v8bf16 = __attribute__((ext_vector_type(8))) __bf16;
using f32x4  = __attribute__((ext_vector_type(4))) float;

// ---------------- CSR build ----------------

__global__ __launch_bounds__(256) void count_kernel(const int* __restrict__ ei,
        int* __restrict__ cnt, int e_in, int n) {
    int e = blockIdx.x * 256 + threadIdx.x;
    int tot = e_in + n;
    if (e >= tot) return;
    int d = (e < e_in) ? ei[e_in + e] : (e - e_in);
    atomicAdd(&cnt[d], 1);
}

__global__ __launch_bounds__(1024) void scan_reduce_kernel(const int* __restrict__ cnt,
        int* __restrict__ blocksum, int n) {
    __shared__ int wsum[16];
    int b = blockIdx.x;
    int base = b * SCAN_CHUNK;
    int t = threadIdx.x;
    int s = 0;
    #pragma unroll
    for (int j = 0; j < 4; ++j) {
        int i = base + t * 4 + j;
        if (i < n) s += cnt[i];
    }
    int lane = t & 63, wid = t >> 6;
    #pragma unroll
    for (int dlt = 32; dlt > 0; dlt >>= 1) s += __shfl_down(s, dlt, 64);
    if (lane == 0) wsum[wid] = s;
    __syncthreads();
    if (t == 0) {
        int tot = 0;
        #pragma unroll
        for (int w = 0; w < 16; ++w) tot += wsum[w];
        blocksum[b] = tot;
    }
}

__global__ __launch_bounds__(1024) void scan_blocksums_kernel(const int* __restrict__ blocksum,
        int* __restrict__ blockoffs, int* __restrict__ offs, int nb, int n) {
    __shared__ int wsum[16];
    __shared__ int carry;
    if (threadIdx.x == 0) carry = 0;
    __syncthreads();
    int lane = threadIdx.x & 63;
    int wid = threadIdx.x >> 6;
    for (int base = 0; base < nb; base += 1024) {
        int i = base + threadIdx.x;
        int v = (i < nb) ? blocksum[i] : 0;
        int x = v;
        #pragma unroll
        for (int dlt = 1; dlt < 64; dlt <<= 1) {
            int y = __shfl_up(x, dlt, 64);
            if (lane >= dlt) x += y;
        }
        if (lane == 63) wsum[wid] = x;
        __syncthreads();
        if (wid == 0) {
            int s = (lane < 16) ? wsum[lane] : 0;
            #pragma unroll
            for (int dlt = 1; dlt < 16; dlt <<= 1) {
                int y = __shfl_up(s, dlt, 64);
                if (lane >= dlt) s += y;
            }
            if (lane < 16) wsum[lane] = s;
        }
        __syncthreads();
        int bincl = x + (wid > 0 ? wsum[wid - 1] : 0);
        int excl = carry + bincl - v;
        if (i < nb) blockoffs[i] = excl;
        __syncthreads();
        if (threadIdx.x == 1023) carry += bincl;
        __syncthreads();
    }
    if (threadIdx.x == 0) { blockoffs[nb] = carry; offs[n] = carry; }
}

__global__ __launch_bounds__(1024) void scan_final_kernel(const int* __restrict__ cnt,
        const int* __restrict__ blockoffs, int* __restrict__ offs, int n) {
    __shared__ int wsum[16];
    int b = blockIdx.x;
    int base = b * SCAN_CHUNK;
    int t = threadIdx.x;
    int i0 = base + t * 4;
    int v[4];
    #pragma unroll
    for (int j = 0; j < 4; ++j) v[j] = (i0 + j < n) ? cnt[i0 + j] : 0;
    int tsum = v[0] + v[1] + v[2] + v[3];
    int lane = t & 63, wid = t >> 6;
    int x = tsum;
    #pragma unroll
    for (int dlt = 1; dlt < 64; dlt <<= 1) {
        int y = __shfl_up(x, dlt, 64);
        if (lane >= dlt) x += y;
    }
    if (lane == 63) wsum[wid] = x;
    __syncthreads();
    if (wid == 0) {
        int s = (lane < 16) ? wsum[lane] : 0;
        #pragma unroll
        for (int dlt = 1; dlt < 16; dlt <<= 1) {
            int y = __shfl_up(s, dlt, 64);
            if (lane >= dlt) s += y;
        }
        if (lane < 16) wsum[lane] = s;
    }
    __syncthreads();
    int incl = x + (wid > 0 ? wsum[wid - 1] : 0);
    int excl = blockoffs[b] + incl - tsum;
    #pragma unroll
    for (int j = 0; j < 4; ++j) {
        if (i0 + j < n) offs[i0 + j] = excl;
        excl += v[j];
    }
}

__global__ __launch_bounds__(256) void scatter_kernel(const int* __restrict__ ei,
        const int* __restrict__ offs, int* __restrict__ cursor,
        int* __restrict__ csr_src, int e_in, int n) {
    int e = blockIdx.x * 256 + threadIdx.x;
    int tot = e_in + n;
    if (e >= tot) return;
    int s, d;
    if (e < e_in) { s = ei[e]; d = ei[e_in + e]; }
    else          { s = e - e_in; d = s; }
    int pos = atomicAdd(&cursor[d], 1);
    csr_src[offs[d] + pos] = s;
}

// ---------------- Per-layer kernels ----------------

// W (fp32, [k][c]) -> Wt (bf16, transposed [c][k]) so MFMA B-fragments are
// 16B-contiguous loads.
__global__ __launch_bounds__(256) void wcvt_kernel(const float* __restrict__ W,
        short* __restrict__ Wt) {
    int t = blockIdx.x * 256 + threadIdx.x;   // 0..16383
    int k = t & (D - 1);
    int c = t >> 7;
    __hip_bfloat16 b = __float2bfloat16(W[(size_t)k * D + c]);
    Wt[(size_t)c * D + k] = *(const short*)&b;
}

// H[n x 128](bf16) = X @ W via mfma_f32_16x16x32_bf16. No LDS, no barriers.
// Block = 4 waves; wave handles 16 rows x 128 cols = 8 col-tiles x 4 k-chunks.
// B frags (each used once) stream from L2-resident Wt; A frags load directly
// from global (verified layout A[m=lane&15][k=quad*8+j]).
// Fused epilogue from fp32 accumulators: hs = H·a_src, hd = H·a_dst.
template<bool BF16IN>
__global__ __launch_bounds__(256) void gemm_mfma_kernel(
        const void* __restrict__ Xv, const short* __restrict__ Wt,
        const float* __restrict__ a_src, const float* __restrict__ a_dst,
        __hip_bfloat16* __restrict__ H, float* __restrict__ hs,
        float* __restrict__ hd, int n) {
    const int lane = threadIdx.x & 63;
    const int wave = threadIdx.x >> 6;
    const int gl = lane & 15;
    const int q = lane >> 4;
    const int row0 = blockIdx.x * 64 + wave * 16;

    int arow = row0 + gl;
    if (arow >= n) arow = n - 1;   // clamped load; stores are guarded below

    f32x4 acc[8];
    #pragma unroll
    for (int t = 0; t < 8; ++t) acc[t] = (f32x4){0.f, 0.f, 0.f, 0.f};

    #pragma unroll
    for (int kc = 0; kc < 4; ++kc) {
        v8bf16 afr;
        if constexpr (BF16IN) {
            const short* Xb = (const short*)Xv;
            afr = *(const v8bf16*)&Xb[(size_t)arow * D + kc * 32 + q * 8];
        } else {
            const float* Xf = (const float*)Xv;
            const float* p = &Xf[(size_t)arow * D + kc * 32 + q * 8];
            float4 x0 = *(const float4*)p;
            float4 x1 = *(const float4*)(p + 4);
            alignas(16) __hip_bfloat16 hb[8];
            hb[0] = __float2bfloat16(x0.x); hb[1] = __float2bfloat16(x0.y);
            hb[2] = __float2bfloat16(x0.z); hb[3] = __float2bfloat16(x0.w);
            hb[4] = __float2bfloat16(x1.x); hb[5] = __float2bfloat16(x1.y);
            hb[6] = __float2bfloat16(x1.z); hb[7] = __float2bfloat16(x1.w);
            afr = *(const v8bf16*)hb;
        }
        #pragma unroll
        for (int t = 0; t < 8; ++t) {
            v8bf16 bfr = *(const v8bf16*)&Wt[(size_t)(t * 16 + gl) * D + kc * 32 + q * 8];
            acc[t] = __builtin_amdgcn_mfma_f32_16x16x32_bf16(afr, bfr, acc[t], 0, 0, 0);
        }
    }

    float asv[8], adv[8];
    #pragma unroll
    for (int t = 0; t < 8; ++t) { asv[t] = a_src[t * 16 + gl]; adv[t] = a_dst[t * 16 + gl]; }

    // C/D layout: col = t*16 + (lane&15), row = row0 + q*4 + reg
    #pragma unroll
    for (int r = 0; r < 4; ++r) {
        int row = row0 + q * 4 + r;
        bool ok = row < n;
        float ps = 0.f, pd = 0.f;
        #pragma unroll
        for (int t = 0; t < 8; ++t) {
            float v = acc[t][r];
            ps = fmaf(v, asv[t], ps);
            pd = fmaf(v, adv[t], pd);
            if (ok) H[(size_t)row * D + t * 16 + gl] = __float2bfloat16(v);
        }
        // lanes q*16..q*16+15 share this row: 16-lane shuffle reduce
        #pragma unroll
        for (int dlt = 8; dlt > 0; dlt >>= 1) {
            ps += __shfl_down(ps, dlt, 16);
            pd += __shfl_down(pd, dlt, 16);
        }
        if (ok && gl == 0) { hs[row] = ps; hd[row] = pd; }
    }
}

// One wave per destination node; 4 edges in flight per trip.
// OUT_BF16: layer-1 path, writes bf16 (consumed only by GEMM2's A operand).
template<bool OUT_BF16>
__global__ __launch_bounds__(256) void aggregate_kernel(
        const __hip_bfloat16* __restrict__ h, const float* __restrict__ hs,
        const float* __restrict__ hd, const int* __restrict__ offs,
        const int* __restrict__ csr_src, const float* __restrict__ bias,
        float* __restrict__ outf, __hip_bfloat16* __restrict__ outb, int n) {
    int node = blockIdx.x * 4 + (threadIdx.x >> 6);
    if (node >= n) return;
    int lane = threadIdx.x & 63;
    int grp = lane >> 4;
    int gl = lane & 15;
    int beg = offs[node], end = offs[node + 1];
    float hdn = hd[node];
    const uint* hp = (const uint*)h;   // 2 bf16 per uint, row stride 64 uints

    float acc[8] = {0.f, 0.f, 0.f, 0.f, 0.f, 0.f, 0.f, 0.f};
    float z = 0.f;
    for (int j = beg; j < end; j += 4) {
        int jj = j + grp;
        bool act = jj < end;
        int s = act ? csr_src[jj] : node;
        float e = hs[s] + hdn;
        e = e > 0.f ? e : NEG_SLOPE * e;
        float wv = act ? __expf(e) : 0.f;
        uint4 raw = *(const uint4*)(hp + ((size_t)s << 6) + (gl << 2));
        float f0 = __uint_as_float(raw.x << 16);
        float f1 = __uint_as_float(raw.x & 0xffff0000u);
        float f2 = __uint_as_float(raw.y << 16);
        float f3 = __uint_as_float(raw.y & 0xffff0000u);
        float f4 = __uint_as_float(raw.z << 16);
        float f5 = __uint_as_float(raw.z & 0xffff0000u);
        float f6 = __uint_as_float(raw.w << 16);
        float f7 = __uint_as_float(raw.w & 0xffff0000u);
        acc[0] = fmaf(wv, f0, acc[0]);
        acc[1] = fmaf(wv, f1, acc[1]);
        acc[2] = fmaf(wv, f2, acc[2]);
        acc[3] = fmaf(wv, f3, acc[3]);
        acc[4] = fmaf(wv, f4, acc[4]);
        acc[5] = fmaf(wv, f5, acc[5]);
        acc[6] = fmaf(wv, f6, acc[6]);
        acc[7] = fmaf(wv, f7, acc[7]);
        z += wv;
    }
    #pragma unroll
    for (int dlt = 32; dlt >= 16; dlt >>= 1) {
        #pragma unroll
        for (int k = 0; k < 8; ++k) acc[k] += __shfl_down(acc[k], dlt, 64);
        z += __shfl_down(z, dlt, 64);
    }
    if (lane < 16) {
        float inv = 1.0f / z;   // self-loop guarantees z > 0
        float4 b0 = *(const float4*)&bias[lane * 8];
        float4 b1 = *(const float4*)&bias[lane * 8 + 4];
        float o[8];
        o[0] = acc[0] * inv + b0.x; o[1] = acc[1] * inv + b0.y;
        o[2] = acc[2] * inv + b0.z; o[3] = acc[3] * inv + b0.w;
        o[4] = acc[4] * inv + b1.x; o[5] = acc[5] * inv + b1.y;
        o[6] = acc[6] * inv + b1.z; o[7] = acc[7] * inv + b1.w;
        #pragma unroll
        for (int k = 0; k < 8; ++k) o[k] = o[k] > 0.f ? o[k] : 0.f;
        if constexpr (OUT_BF16) {
            alignas(16) __hip_bfloat16 ob[8];
            #pragma unroll
            for (int k = 0; k < 8; ++k) ob[k] = __float2bfloat16(o[k]);
            *(uint4*)&outb[(size_t)node * D + lane * 8] = *(const uint4*)ob;
        } else {
            float* op = outf + (size_t)node * D + lane * 8;
            *(float4*)op = make_float4(o[0], o[1], o[2], o[3]);
            *(float4*)(op + 4) = make_float4(o[4], o[5], o[6], o[7]);
        }
    }
}

// ---------------- Orchestration ----------------

extern "C" void kernel_launch(void* const* d_in, const int* in_sizes, int n_in,
                              void* d_out, int out_size, void* d_ws, size_t ws_size,
                              hipStream_t stream) {
    const float* x      = (const float*)d_in[0];
    const int*   ei     = (const int*)d_in[1];
    const float* W1     = (const float*)d_in[2];
    const float* a_src1 = (const float*)d_in[3];
    const float* a_dst1 = (const float*)d_in[4];
    const float* b1     = (const float*)d_in[5];
    const float* W2     = (const float*)d_in[6];
    const float* a_src2 = (const float*)d_in[7];
    const float* a_dst2 = (const float*)d_in[8];
    const float* b2     = (const float*)d_in[9];

    int n    = in_sizes[0] / D;       // 100000
    int e_in = in_sizes[1] / 2;       // 625000
    int e_tot = e_in + n;             // 725000
    int nsb = (n + SCAN_CHUNK - 1) / SCAN_CHUNK;

    // ws: h(bf16) | t(bf16) | Wt(bf16) | hs | hd | cnt | offs | cursor | blocksum | blockoffs | csr
    __hip_bfloat16* h  = (__hip_bfloat16*)d_ws;
    __hip_bfloat16* tb = h + (size_t)n * D;
    short* Wt       = (short*)(tb + (size_t)n * D);
    float* hs       = (float*)(Wt + D * D);
    float* hd       = hs + n;
    int*   cnt      = (int*)(hd + n);
    int*   offs     = cnt + n;
    int*   cursor   = offs + n + 1;
    int*   blocksum = cursor + n;
    int*   blockoffs= blocksum + nsb;
    int*   csr      = blockoffs + nsb + 1;

    int eb = (e_tot + 255) / 256;
    int nb4 = (n + 3) / 4;
    int gb = (n + 63) / 64;

    hipMemsetAsync(cnt, 0, (size_t)n * sizeof(int), stream);
    hipMemsetAsync(cursor, 0, (size_t)n * sizeof(int), stream);
    count_kernel<<<eb, 256, 0, stream>>>(ei, cnt, e_in, n);
    scan_reduce_kernel<<<nsb, 1024, 0, stream>>>(cnt, blocksum, n);
    scan_blocksums_kernel<<<1, 1024, 0, stream>>>(blocksum, blockoffs, offs, nsb, n);
    scan_final_kernel<<<nsb, 1024, 0, stream>>>(cnt, blockoffs, offs, n);
    scatter_kernel<<<eb, 256, 0, stream>>>(ei, offs, cursor, csr, e_in, n);

    // Layer 1
    wcvt_kernel<<<64, 256, 0, stream>>>(W1, Wt);
    gemm_mfma_kernel<false><<<gb, 256, 0, stream>>>(x, Wt, a_src1, a_dst1, h, hs, hd, n);
    aggregate_kernel<true><<<nb4, 256, 0, stream>>>(h, hs, hd, offs, csr, b1, nullptr, tb, n);

    // Layer 2
    wcvt_kernel<<<64, 256, 0, stream>>>(W2, Wt);
    gemm_mfma_kernel<true><<<gb, 256, 0, stream>>>(tb, Wt, a_src2, a_dst2, h, hs, hd, n);
    aggregate_kernel<false><<<nb4, 256, 0, stream>>>(h, hs, hd, offs, csr, b2, (float*)d_out, nullptr, n);
}

// Round 5
// 314.141 us; speedup vs baseline: 1.8400x; 1.1659x over previous
//
#include <hip/hip_runtime.h>
#include <hip/hip_bf16.h>

#define D 128
#define NEG_SLOPE 0.2f
#define SCAN_CHUNK 4096   // elements per block in hierarchical scan

using v8bf16 = __attribute__((ext_vector_type(8))) __bf16;
using f32x4  = __attribute__((ext_vector_type(4))) float;

// ---------------- CSR build (one atomic pass) ----------------

// Pass 1: per-edge rank within its destination (the ONLY atomic pass).
__global__ __launch_bounds__(256) void rank_kernel(const int* __restrict__ ei,
        int* __restrict__ cnt, int* __restrict__ rank, int e_in, int n) {
    int e = blockIdx.x * 256 + threadIdx.x;
    int tot = e_in + n;
    if (e >= tot) return;
    int d = (e < e_in) ? ei[e_in + e] : (e - e_in);
    rank[e] = atomicAdd(&cnt[d], 1);
}

__global__ __launch_bounds__(1024) void scan_reduce_kernel(const int* __restrict__ cnt,
        int* __restrict__ blocksum, int n) {
    __shared__ int wsum[16];
    int b = blockIdx.x;
    int base = b * SCAN_CHUNK;
    int t = threadIdx.x;
    int s = 0;
    #pragma unroll
    for (int j = 0; j < 4; ++j) {
        int i = base + t * 4 + j;
        if (i < n) s += cnt[i];
    }
    int lane = t & 63, wid = t >> 6;
    #pragma unroll
    for (int dlt = 32; dlt > 0; dlt >>= 1) s += __shfl_down(s, dlt, 64);
    if (lane == 0) wsum[wid] = s;
    __syncthreads();
    if (t == 0) {
        int tot = 0;
        #pragma unroll
        for (int w = 0; w < 16; ++w) tot += wsum[w];
        blocksum[b] = tot;
    }
}

__global__ __launch_bounds__(1024) void scan_blocksums_kernel(const int* __restrict__ blocksum,
        int* __restrict__ blockoffs, int* __restrict__ offs, int nb, int n) {
    __shared__ int wsum[16];
    __shared__ int carry;
    if (threadIdx.x == 0) carry = 0;
    __syncthreads();
    int lane = threadIdx.x & 63;
    int wid = threadIdx.x >> 6;
    for (int base = 0; base < nb; base += 1024) {
        int i = base + threadIdx.x;
        int v = (i < nb) ? blocksum[i] : 0;
        int x = v;
        #pragma unroll
        for (int dlt = 1; dlt < 64; dlt <<= 1) {
            int y = __shfl_up(x, dlt, 64);
            if (lane >= dlt) x += y;
        }
        if (lane == 63) wsum[wid] = x;
        __syncthreads();
        if (wid == 0) {
            int s = (lane < 16) ? wsum[lane] : 0;
            #pragma unroll
            for (int dlt = 1; dlt < 16; dlt <<= 1) {
                int y = __shfl_up(s, dlt, 64);
                if (lane >= dlt) s += y;
            }
            if (lane < 16) wsum[lane] = s;
        }
        __syncthreads();
        int bincl = x + (wid > 0 ? wsum[wid - 1] : 0);
        int excl = carry + bincl - v;
        if (i < nb) blockoffs[i] = excl;
        __syncthreads();
        if (threadIdx.x == 1023) carry += bincl;
        __syncthreads();
    }
    if (threadIdx.x == 0) { blockoffs[nb] = carry; offs[n] = carry; }
}

__global__ __launch_bounds__(1024) void scan_final_kernel(const int* __restrict__ cnt,
        const int* __restrict__ blockoffs, int* __restrict__ offs, int n) {
    __shared__ int wsum[16];
    int b = blockIdx.x;
    int base = b * SCAN_CHUNK;
    int t = threadIdx.x;
    int i0 = base + t * 4;
    int v[4];
    #pragma unroll
    for (int j = 0; j < 4; ++j) v[j] = (i0 + j < n) ? cnt[i0 + j] : 0;
    int tsum = v[0] + v[1] + v[2] + v[3];
    int lane = t & 63, wid = t >> 6;
    int x = tsum;
    #pragma unroll
    for (int dlt = 1; dlt < 64; dlt <<= 1) {
        int y = __shfl_up(x, dlt, 64);
        if (lane >= dlt) x += y;
    }
    if (lane == 63) wsum[wid] = x;
    __syncthreads();
    if (wid == 0) {
        int s = (lane < 16) ? wsum[lane] : 0;
        #pragma unroll
        for (int dlt = 1; dlt < 16; dlt <<= 1) {
            int y = __shfl_up(s, dlt, 64);
            if (lane >= dlt) s += y;
        }
        if (lane < 16) wsum[lane] = s;
    }
    __syncthreads();
    int incl = x + (wid > 0 ? wsum[wid - 1] : 0);
    int excl = blockoffs[b] + incl - tsum;
    #pragma unroll
    for (int j = 0; j < 4; ++j) {
        if (i0 + j < n) offs[i0 + j] = excl;
        excl += v[j];
    }
}

// Pass 3: atomic-free placement.
__global__ __launch_bounds__(256) void place_kernel(const int* __restrict__ ei,
        const int* __restrict__ offs, const int* __restrict__ rank,
        int* __restrict__ csr_src, int e_in, int n) {
    int e = blockIdx.x * 256 + threadIdx.x;
    int tot = e_in + n;
    if (e >= tot) return;
    int s, d;
    if (e < e_in) { s = ei[e]; d = ei[e_in + e]; }
    else          { s = e - e_in; d = s; }
    csr_src[offs[d] + rank[e]] = s;
}

// ---------------- Per-layer kernels ----------------

// W1,W2 (fp32, [k][c]) -> Wt1,Wt2 (bf16, transposed [c][k]), one dispatch.
__global__ __launch_bounds__(256) void wcvt_kernel(const float* __restrict__ W1,
        const float* __restrict__ W2, short* __restrict__ Wt1,
        short* __restrict__ Wt2) {
    int t = blockIdx.x * 256 + threadIdx.x;   // 0..32767
    int which = t >> 14;
    int idx = t & 16383;
    int k = idx & (D - 1);
    int c = idx >> 7;
    const float* W = which ? W2 : W1;
    short* Wt = which ? Wt2 : Wt1;
    __hip_bfloat16 b = __float2bfloat16(W[(size_t)k * D + c]);
    Wt[(size_t)c * D + k] = *(const short*)&b;
}

// H[n x 128](bf16) = X @ W via mfma_f32_16x16x32_bf16. No LDS, no barriers.
// Fused epilogue from fp32 accumulators: hs = H·a_src, hd = H·a_dst.
template<bool BF16IN>
__global__ __launch_bounds__(256) void gemm_mfma_kernel(
        const void* __restrict__ Xv, const short* __restrict__ Wt,
        const float* __restrict__ a_src, const float* __restrict__ a_dst,
        __hip_bfloat16* __restrict__ H, float* __restrict__ hs,
        float* __restrict__ hd, int n) {
    const int lane = threadIdx.x & 63;
    const int wave = threadIdx.x >> 6;
    const int gl = lane & 15;
    const int q = lane >> 4;
    const int row0 = blockIdx.x * 64 + wave * 16;

    int arow = row0 + gl;
    if (arow >= n) arow = n - 1;   // clamped load; stores are guarded below

    f32x4 acc[8];
    #pragma unroll
    for (int t = 0; t < 8; ++t) acc[t] = (f32x4){0.f, 0.f, 0.f, 0.f};

    #pragma unroll
    for (int kc = 0; kc < 4; ++kc) {
        v8bf16 afr;
        if constexpr (BF16IN) {
            const short* Xb = (const short*)Xv;
            afr = *(const v8bf16*)&Xb[(size_t)arow * D + kc * 32 + q * 8];
        } else {
            const float* Xf = (const float*)Xv;
            const float* p = &Xf[(size_t)arow * D + kc * 32 + q * 8];
            float4 x0 = *(const float4*)p;
            float4 x1 = *(const float4*)(p + 4);
            alignas(16) __hip_bfloat16 hb[8];
            hb[0] = __float2bfloat16(x0.x); hb[1] = __float2bfloat16(x0.y);
            hb[2] = __float2bfloat16(x0.z); hb[3] = __float2bfloat16(x0.w);
            hb[4] = __float2bfloat16(x1.x); hb[5] = __float2bfloat16(x1.y);
            hb[6] = __float2bfloat16(x1.z); hb[7] = __float2bfloat16(x1.w);
            afr = *(const v8bf16*)hb;
        }
        #pragma unroll
        for (int t = 0; t < 8; ++t) {
            v8bf16 bfr = *(const v8bf16*)&Wt[(size_t)(t * 16 + gl) * D + kc * 32 + q * 8];
            acc[t] = __builtin_amdgcn_mfma_f32_16x16x32_bf16(afr, bfr, acc[t], 0, 0, 0);
        }
    }

    float asv[8], adv[8];
    #pragma unroll
    for (int t = 0; t < 8; ++t) { asv[t] = a_src[t * 16 + gl]; adv[t] = a_dst[t * 16 + gl]; }

    // C/D layout: col = t*16 + (lane&15), row = row0 + q*4 + reg
    #pragma unroll
    for (int r = 0; r < 4; ++r) {
        int row = row0 + q * 4 + r;
        bool ok = row < n;
        float ps = 0.f, pd = 0.f;
        #pragma unroll
        for (int t = 0; t < 8; ++t) {
            float v = acc[t][r];
            ps = fmaf(v, asv[t], ps);
            pd = fmaf(v, adv[t], pd);
            if (ok) H[(size_t)row * D + t * 16 + gl] = __float2bfloat16(v);
        }
        #pragma unroll
        for (int dlt = 8; dlt > 0; dlt >>= 1) {
            ps += __shfl_down(ps, dlt, 16);
            pd += __shfl_down(pd, dlt, 16);
        }
        if (ok && gl == 0) { hs[row] = ps; hd[row] = pd; }
    }
}

// Two nodes per 128-thread block, one wave per node; 8 edges in flight per trip
// (lane group grp=lane>>4 owns edges j+2*grp and j+2*grp+1; gl=lane&15 owns
// 16B of the 256B bf16 row). Within-node edge order is free (sum is
// order-invariant up to fp32 rounding).
template<bool OUT_BF16>
__global__ __launch_bounds__(128) void aggregate_kernel(
        const __hip_bfloat16* __restrict__ h, const float* __restrict__ hs,
        const float* __restrict__ hd, const int* __restrict__ offs,
        const int* __restrict__ csr_src, const float* __restrict__ bias,
        float* __restrict__ outf, __hip_bfloat16* __restrict__ outb, int n) {
    int node = blockIdx.x * 2 + (threadIdx.x >> 6);
    if (node >= n) return;
    int lane = threadIdx.x & 63;
    int grp = lane >> 4;
    int gl = lane & 15;
    int beg = offs[node], end = offs[node + 1];
    float hdn = hd[node];
    const uint* hp = (const uint*)h;   // 2 bf16 per uint, row stride 64 uints

    float acc[8] = {0.f, 0.f, 0.f, 0.f, 0.f, 0.f, 0.f, 0.f};
    float z = 0.f;
    for (int j = beg; j < end; j += 8) {
        int jj0 = j + 2 * grp;
        int jj1 = jj0 + 1;
        bool a0 = jj0 < end, a1 = jj1 < end;
        int s0 = a0 ? csr_src[jj0] : node;
        int s1 = a1 ? csr_src[jj1] : node;
        float e0 = hs[s0] + hdn;
        float e1 = hs[s1] + hdn;
        e0 = e0 > 0.f ? e0 : NEG_SLOPE * e0;
        e1 = e1 > 0.f ? e1 : NEG_SLOPE * e1;
        float w0 = a0 ? __expf(e0) : 0.f;
        float w1 = a1 ? __expf(e1) : 0.f;
        uint4 r0 = *(const uint4*)(hp + ((size_t)s0 << 6) + (gl << 2));
        uint4 r1 = *(const uint4*)(hp + ((size_t)s1 << 6) + (gl << 2));
        acc[0] = fmaf(w0, __uint_as_float(r0.x << 16), acc[0]);
        acc[1] = fmaf(w0, __uint_as_float(r0.x & 0xffff0000u), acc[1]);
        acc[2] = fmaf(w0, __uint_as_float(r0.y << 16), acc[2]);
        acc[3] = fmaf(w0, __uint_as_float(r0.y & 0xffff0000u), acc[3]);
        acc[4] = fmaf(w0, __uint_as_float(r0.z << 16), acc[4]);
        acc[5] = fmaf(w0, __uint_as_float(r0.z & 0xffff0000u), acc[5]);
        acc[6] = fmaf(w0, __uint_as_float(r0.w << 16), acc[6]);
        acc[7] = fmaf(w0, __uint_as_float(r0.w & 0xffff0000u), acc[7]);
        acc[0] = fmaf(w1, __uint_as_float(r1.x << 16), acc[0]);
        acc[1] = fmaf(w1, __uint_as_float(r1.x & 0xffff0000u), acc[1]);
        acc[2] = fmaf(w1, __uint_as_float(r1.y << 16), acc[2]);
        acc[3] = fmaf(w1, __uint_as_float(r1.y & 0xffff0000u), acc[3]);
        acc[4] = fmaf(w1, __uint_as_float(r1.z << 16), acc[4]);
        acc[5] = fmaf(w1, __uint_as_float(r1.z & 0xffff0000u), acc[5]);
        acc[6] = fmaf(w1, __uint_as_float(r1.w << 16), acc[6]);
        acc[7] = fmaf(w1, __uint_as_float(r1.w & 0xffff0000u), acc[7]);
        z += w0 + w1;
    }
    // combine the 4 edge groups -> lanes 0..15 hold the full row
    #pragma unroll
    for (int dlt = 32; dlt >= 16; dlt >>= 1) {
        #pragma unroll
        for (int k = 0; k < 8; ++k) acc[k] += __shfl_down(acc[k], dlt, 64);
        z += __shfl_down(z, dlt, 64);
    }
    if (lane < 16) {
        float inv = 1.0f / z;   // self-loop guarantees z > 0
        float4 b0 = *(const float4*)&bias[lane * 8];
        float4 b1 = *(const float4*)&bias[lane * 8 + 4];
        float o[8];
        o[0] = acc[0] * inv + b0.x; o[1] = acc[1] * inv + b0.y;
        o[2] = acc[2] * inv + b0.z; o[3] = acc[3] * inv + b0.w;
        o[4] = acc[4] * inv + b1.x; o[5] = acc[5] * inv + b1.y;
        o[6] = acc[6] * inv + b1.z; o[7] = acc[7] * inv + b1.w;
        #pragma unroll
        for (int k = 0; k < 8; ++k) o[k] = o[k] > 0.f ? o[k] : 0.f;
        if constexpr (OUT_BF16) {
            alignas(16) __hip_bfloat16 ob[8];
            #pragma unroll
            for (int k = 0; k < 8; ++k) ob[k] = __float2bfloat16(o[k]);
            *(uint4*)&outb[(size_t)node * D + lane * 8] = *(const uint4*)ob;
        } else {
            float* op = outf + (size_t)node * D + lane * 8;
            *(float4*)op = make_float4(o[0], o[1], o[2], o[3]);
            *(float4*)(op + 4) = make_float4(o[4], o[5], o[6], o[7]);
        }
    }
}

// ---------------- Orchestration ----------------

extern "C" void kernel_launch(void* const* d_in, const int* in_sizes, int n_in,
                              void* d_out, int out_size, void* d_ws, size_t ws_size,
                              hipStream_t stream) {
    const float* x      = (const float*)d_in[0];
    const int*   ei     = (const int*)d_in[1];
    const float* W1     = (const float*)d_in[2];
    const float* a_src1 = (const float*)d_in[3];
    const float* a_dst1 = (const float*)d_in[4];
    const float* b1     = (const float*)d_in[5];
    const float* W2     = (const float*)d_in[6];
    const float* a_src2 = (const float*)d_in[7];
    const float* a_dst2 = (const float*)d_in[8];
    const float* b2     = (const float*)d_in[9];

    int n    = in_sizes[0] / D;       // 100000
    int e_in = in_sizes[1] / 2;       // 625000
    int e_tot = e_in + n;             // 725000
    int nsb = (n + SCAN_CHUNK - 1) / SCAN_CHUNK;

    // ws: h(bf16) | t(bf16) | Wt1 | Wt2 | hs | hd | cnt | offs | rank | blocksum | blockoffs | csr
    __hip_bfloat16* h  = (__hip_bfloat16*)d_ws;
    __hip_bfloat16* tb = h + (size_t)n * D;
    short* Wt1      = (short*)(tb + (size_t)n * D);
    short* Wt2      = Wt1 + D * D;
    float* hs       = (float*)(Wt2 + D * D);
    float* hd       = hs + n;
    int*   cnt      = (int*)(hd + n);
    int*   offs     = cnt + n;
    int*   rank     = offs + n + 1;
    int*   blocksum = rank + e_tot;
    int*   blockoffs= blocksum + nsb;
    int*   csr      = blockoffs + nsb + 1;

    int eb = (e_tot + 255) / 256;
    int nb2 = (n + 1) / 2;
    int gb = (n + 63) / 64;

    hipMemsetAsync(cnt, 0, (size_t)n * sizeof(int), stream);
    wcvt_kernel<<<128, 256, 0, stream>>>(W1, W2, Wt1, Wt2);
    rank_kernel<<<eb, 256, 0, stream>>>(ei, cnt, rank, e_in, n);
    scan_reduce_kernel<<<nsb, 1024, 0, stream>>>(cnt, blocksum, n);
    scan_blocksums_kernel<<<1, 1024, 0, stream>>>(blocksum, blockoffs, offs, nsb, n);
    scan_final_kernel<<<nsb, 1024, 0, stream>>>(cnt, blockoffs, offs, n);
    place_kernel<<<eb, 256, 0, stream>>>(ei, offs, rank, csr, e_in, n);

    // Layer 1
    gemm_mfma_kernel<false><<<gb, 256, 0, stream>>>(x, Wt1, a_src1, a_dst1, h, hs, hd, n);
    aggregate_kernel<true><<<nb2, 128, 0, stream>>>(h, hs, hd, offs, csr, b1, nullptr, tb, n);

    // Layer 2
    gemm_mfma_kernel<true><<<gb, 256, 0, stream>>>(tb, Wt2, a_src2, a_dst2, h, hs, hd, n);
    aggregate_kernel<false><<<nb2, 128, 0, stream>>>(h, hs, hd, offs, csr, b2, (float*)d_out, nullptr, n);
}